// Round 3
// baseline (1792.307 us; speedup 1.0000x reference)
//
#include <hip/hip_runtime.h>
#include <stdint.h>

// GRU forward: V=32000 E=128 H=256 B=8 S=512.
// Reference dtypes are float32; a detector kernel resolves f32-vs-bf16 storage
// at runtime and exactly one templated variant of each kernel does the work.
// ws: gi f32 [512][8][768] (12.58MB) | hidden fp16 [4096][256] (2.1MB) | flag

typedef __attribute__((ext_vector_type(8))) _Float16 half8;   // 4 VGPRs
typedef __attribute__((ext_vector_type(4))) _Float16 half4;   // 2 VGPRs
typedef __attribute__((ext_vector_type(4))) float float4v;
typedef __attribute__((ext_vector_type(4))) float facc4;      // MFMA acc
typedef __attribute__((ext_vector_type(4))) unsigned short ushort4v;

#define GI_BYTES   (512 * 8 * 768 * 4)        // 12582912
#define HID_BYTES  (4096 * 256 * 2)           // 2097152
#define FLAG_OFF   (GI_BYTES + HID_BYTES)

__device__ __forceinline__ float b2f(unsigned short u) {
  union { unsigned int i; float f; } v; v.i = ((unsigned int)u) << 16; return v.f;
}
__device__ __forceinline__ unsigned short f2b(float f) {
  union { float f; unsigned int i; } v; v.f = f;
  unsigned int r = v.i + 0x7FFFu + ((v.i >> 16) & 1u);  // RNE
  return (unsigned short)(r >> 16);
}
template<bool BF> __device__ __forceinline__ float ldf(const void* p, int i) {
  if constexpr (BF) return b2f(((const unsigned short*)p)[i]);
  else              return ((const float*)p)[i];
}
template<bool BF> __device__ __forceinline__ float4v ld4(const void* p, int i) {
  float4v r;
  if constexpr (BF) {
    ushort4v u = *reinterpret_cast<const ushort4v*>((const unsigned short*)p + i);
#pragma unroll
    for (int j = 0; j < 4; ++j) r[j] = b2f(u[j]);
  } else {
    r = *reinterpret_cast<const float4v*>((const float*)p + i);
  }
  return r;
}

// ---- dtype detector: bf16 storage => low u16 of each u32 word has a small-
// value bf16 exponent pattern; f32 storage => those bits are uniform mantissa.
__global__ void k_detect(const unsigned int* __restrict__ emb_raw,
                         int* __restrict__ flag) {
  int tid = threadIdx.x;
  unsigned int u = emb_raw[tid];
  unsigned int lo = u & 0xFFFFu;
  unsigned int ex = (lo >> 7) & 0xFFu;        // bf16 exponent field
  int hit = ((ex >= 96u && ex <= 127u) || lo == 0u) ? 1 : 0;
  unsigned long long m = __ballot(hit);
  if (tid == 0) flag[0] = (__popcll(m) >= 40) ? 1 : 0;
}

// ---- kernel 1: gi[s][b][g] = emb[t[b,s]] . w_ih[g,:] + b_ih[g]  (f32 out) ----
template<bool BF>
__global__ __launch_bounds__(256, 4) void k_gi(
    const int* __restrict__ flag, const int* __restrict__ t,
    const void* __restrict__ emb, const void* __restrict__ w_ih,
    const void* __restrict__ b_ih, float* __restrict__ gi)
{
  if (*flag != (BF ? 1 : 0)) return;
  alignas(16) __shared__ float x_lds[4][128];
  const int n0 = blockIdx.x * 4;               // 4 tokens per block
  const int tid = threadIdx.x;
  for (int i = tid; i < 512; i += 256) {
    int tk = i >> 7, e = i & 127;
    int n = n0 + tk, s = n >> 3, b = n & 7;
    int tok = t[b * 512 + s];
    x_lds[tk][e] = ldf<BF>(emb, tok * 128 + e);
  }
  __syncthreads();
#pragma unroll
  for (int gg = 0; gg < 3; ++gg) {
    int g = gg * 256 + tid;
    float bias = ldf<BF>(b_ih, g);
    float a0 = bias, a1 = bias, a2 = bias, a3 = bias;
    for (int kb = 0; kb < 32; ++kb) {
      float4v w4 = ld4<BF>(w_ih, g * 128 + kb * 4);
#pragma unroll
      for (int j = 0; j < 4; ++j) {
        float w = w4[j]; int k = kb * 4 + j;
        a0 = fmaf(w, x_lds[0][k], a0);
        a1 = fmaf(w, x_lds[1][k], a1);
        a2 = fmaf(w, x_lds[2][k], a2);
        a3 = fmaf(w, x_lds[3][k], a3);
      }
    }
    gi[(n0 + 0) * 768 + g] = a0;
    gi[(n0 + 1) * 768 + g] = a1;
    gi[(n0 + 2) * 768 + g] = a2;
    gi[(n0 + 3) * 768 + g] = a3;
  }
}

// ---- kernel 2: serial GRU scan, single workgroup, 8 waves ----
// Per step gh[8,768] = h[8,256] @ w_hh^T via fp16 mfma 16x16x32 (M=16 pad).
// wave w holds 6 N-tiles of w_hh in regs (48 half8 = 192 VGPRs).
template<bool BF>
__global__ __launch_bounds__(512, 2) void k_scan(
    const int* __restrict__ flag, const void* __restrict__ w_hh,
    const void* __restrict__ b_hh, const void* __restrict__ h0,
    const float* __restrict__ gi, _Float16* __restrict__ hidden)
{
  if (*flag != (BF ? 1 : 0)) return;
  alignas(16) __shared__ _Float16 a_lds[4096];   // A-frag layout, 8KB
  alignas(16) __shared__ float gh_lds[8 * 772];  // [b][gate], pad, 24.7KB
  alignas(16) __shared__ float bhh_lds[768];

  const int tid = threadIdx.x;
  const int wave = tid >> 6, lane = tid & 63;
  const int l15 = lane & 15, q = lane >> 4;
  const int b = tid & 7, jb = tid >> 3, j0 = jb * 4;   // gates ownership
  const int kt0 = jb >> 3, q0 = (jb >> 1) & 3, off0 = (jb & 1) * 4;

  half8 bfr[6][8];   // B[k][n] = w_hh[n][k]; lane: n=n0+l15, k=kt*32+q*8+j
#pragma unroll
  for (int tt = 0; tt < 6; ++tt) {
    int nrow = wave * 96 + tt * 16 + l15;
#pragma unroll
    for (int kt = 0; kt < 8; ++kt) {
      int base = nrow * 256 + kt * 32 + q * 8;
      float4v x0 = ld4<BF>(w_hh, base), x1 = ld4<BF>(w_hh, base + 4);
      half8 h;
#pragma unroll
      for (int j = 0; j < 4; ++j) { h[j] = (_Float16)x0[j]; h[4 + j] = (_Float16)x1[j]; }
      bfr[tt][kt] = h;
    }
  }

  for (int i = tid; i < 4096; i += 512) a_lds[i] = (_Float16)0.f;
  for (int i = tid; i < 768; i += 512) bhh_lds[i] = ldf<BF>(b_hh, i);
  __syncthreads();

  float hreg[4];
  {
    float4v h04 = ld4<BF>(h0, j0);   // h0 broadcast over batch
    half4 h4;
#pragma unroll
    for (int i = 0; i < 4; ++i) { hreg[i] = h04[i]; h4[i] = (_Float16)h04[i]; }
    *reinterpret_cast<half4*>(&a_lds[kt0 * 512 + (q0 * 16 + b) * 8 + off0]) = h4;
  }
  __syncthreads();

  for (int s = 0; s < 512; ++s) {
    facc4 acc[6] = {};
#pragma unroll
    for (int kt = 0; kt < 8; ++kt) {
      half8 a = *reinterpret_cast<const half8*>(&a_lds[kt * 512 + lane * 8]);
#pragma unroll
      for (int tt = 0; tt < 6; ++tt)
        acc[tt] = __builtin_amdgcn_mfma_f32_16x16x32_f16(a, bfr[tt][kt],
                                                         acc[tt], 0, 0, 0);
    }
    // issue gi loads after MFMA block (keeps regs low during MFMA)
    const float* gis = gi + s * 6144 + b * 768 + j0;
    float4v g_r = *reinterpret_cast<const float4v*>(gis);
    float4v g_z = *reinterpret_cast<const float4v*>(gis + 256);
    float4v g_n = *reinterpret_cast<const float4v*>(gis + 512);
    // C layout: col=l15 (gate col), row=q*4+i (batch). Rows 0..7 real.
    if (q < 2) {
#pragma unroll
      for (int tt = 0; tt < 6; ++tt) {
        int nrow = wave * 96 + tt * 16 + l15;
#pragma unroll
        for (int i = 0; i < 4; ++i)
          gh_lds[(q * 4 + i) * 772 + nrow] = acc[tt][i] + bhh_lds[nrow];
      }
    }
    __syncthreads();

    const float* ghb = gh_lds + b * 772;
    half4 hb;
#pragma unroll
    for (int i = 0; i < 4; ++i) {
      int j = j0 + i;
      float r = 1.f / (1.f + __expf(-(g_r[i] + ghb[j])));
      float z = 1.f / (1.f + __expf(-(g_z[i] + ghb[256 + j])));
      float xn = g_n[i] + r * ghb[512 + j];
      float e2 = __expf(2.f * xn);
      float nn = 1.f - 2.f / (e2 + 1.f);           // tanh
      float hnew = (1.f - z) * nn + z * hreg[i];
      hreg[i] = hnew;                              // f32 across steps
      hb[i] = (_Float16)hnew;
    }
    *reinterpret_cast<half4*>(&a_lds[kt0 * 512 + (q0 * 16 + b) * 8 + off0]) = hb;
    *reinterpret_cast<half4*>(hidden + (b * 512 + s) * 256 + j0) = hb;
    __syncthreads();
  }
}

// ---- kernel 3: out[tok][v] = hidden[tok,:] . w_out[v,:] + b_out[v] ----
template<bool BF>
__global__ __launch_bounds__(256, 2) void k_out(
    const int* __restrict__ flag, const _Float16* __restrict__ hidden,
    const void* __restrict__ w_out, const void* __restrict__ b_out,
    void* __restrict__ out)
{
  if (*flag != (BF ? 1 : 0)) return;
  alignas(16) __shared__ _Float16 Asm[128 * 72];  // [m][k], +8 pad
  alignas(16) __shared__ _Float16 Bsm[128 * 72];  // [n][k], +8 pad
  const int bid = blockIdx.x;
  const int m0 = (bid & 31) * 128;     // 32 m-blocks inner: w_out reuse
  const int n0 = (bid >> 5) * 128;     // 250 n-blocks
  const int tid = threadIdx.x;
  const int wave = tid >> 6, lane = tid & 63;
  const int l15 = lane & 15, q = lane >> 4;
  const int wm = (wave >> 1) * 64, wn = (wave & 1) * 64;

  facc4 acc[4][4] = {};
  float bo[4];
#pragma unroll
  for (int nt = 0; nt < 4; ++nt)
    bo[nt] = ldf<BF>(b_out, n0 + wn + nt * 16 + l15);

  for (int kk = 0; kk < 4; ++kk) {
    int k0 = kk * 64;
#pragma unroll
    for (int r = 0; r < 4; ++r) {
      int row = r * 32 + (tid >> 3);
      int ch = tid & 7;
      *reinterpret_cast<half8*>(&Asm[row * 72 + ch * 8]) =
          *reinterpret_cast<const half8*>(hidden + (m0 + row) * 256 + k0 + ch * 8);
      int wbase = (n0 + row) * 256 + k0 + ch * 8;
      float4v w0 = ld4<BF>(w_out, wbase), w1 = ld4<BF>(w_out, wbase + 4);
      half8 hB;
#pragma unroll
      for (int j = 0; j < 4; ++j) { hB[j] = (_Float16)w0[j]; hB[4 + j] = (_Float16)w1[j]; }
      *reinterpret_cast<half8*>(&Bsm[row * 72 + ch * 8]) = hB;
    }
    __syncthreads();
#pragma unroll
    for (int kt = 0; kt < 2; ++kt) {
      int koff = kt * 32 + q * 8;
      half8 af[4], bf[4];
#pragma unroll
      for (int mt = 0; mt < 4; ++mt)
        af[mt] = *reinterpret_cast<const half8*>(&Asm[(wm + mt * 16 + l15) * 72 + koff]);
#pragma unroll
      for (int nt = 0; nt < 4; ++nt)
        bf[nt] = *reinterpret_cast<const half8*>(&Bsm[(wn + nt * 16 + l15) * 72 + koff]);
#pragma unroll
      for (int mt = 0; mt < 4; ++mt)
#pragma unroll
        for (int nt = 0; nt < 4; ++nt)
          acc[mt][nt] = __builtin_amdgcn_mfma_f32_16x16x32_f16(
              af[mt], bf[nt], acc[mt][nt], 0, 0, 0);
    }
    __syncthreads();
  }
#pragma unroll
  for (int mt = 0; mt < 4; ++mt) {
#pragma unroll
    for (int i = 0; i < 4; ++i) {
      int row = m0 + wm + mt * 16 + q * 4 + i;
#pragma unroll
      for (int nt = 0; nt < 4; ++nt) {
        int col = n0 + wn + nt * 16 + l15;
        float val = acc[mt][nt][i] + bo[nt];
        if constexpr (BF) ((unsigned short*)out)[row * 32000 + col] = f2b(val);
        else              ((float*)out)[row * 32000 + col] = val;
      }
    }
  }
}

extern "C" void kernel_launch(void* const* d_in, const int* in_sizes, int n_in,
                              void* d_out, int out_size, void* d_ws, size_t ws_size,
                              hipStream_t stream) {
  const int* t     = (const int*)d_in[0];
  const void* emb  = d_in[1];
  const void* h0   = d_in[2];
  const void* w_ih = d_in[3];
  const void* w_hh = d_in[4];
  const void* b_ih = d_in[5];
  const void* b_hh = d_in[6];
  const void* w_out = d_in[7];
  const void* b_out = d_in[8];

  float*     gi     = (float*)d_ws;
  _Float16*  hidden = (_Float16*)((char*)d_ws + GI_BYTES);
  int*       flag   = (int*)((char*)d_ws + FLAG_OFF);

  k_detect<<<1, 64, 0, stream>>>((const unsigned int*)emb, flag);

  k_gi<false><<<1024, 256, 0, stream>>>(flag, t, emb, w_ih, b_ih, gi);
  k_gi<true> <<<1024, 256, 0, stream>>>(flag, t, emb, w_ih, b_ih, gi);

  k_scan<false><<<1, 512, 0, stream>>>(flag, w_hh, b_hh, h0, gi, hidden);
  k_scan<true> <<<1, 512, 0, stream>>>(flag, w_hh, b_hh, h0, gi, hidden);

  k_out<false><<<8000, 256, 0, stream>>>(flag, hidden, w_out, b_out, d_out);
  k_out<true> <<<8000, 256, 0, stream>>>(flag, hidden, w_out, b_out, d_out);
}